// Round 5
// baseline (191.809 us; speedup 1.0000x reference)
//
#include <hip/hip_runtime.h>
#include <math.h>

#define L 16384
#define H 128
#define P 256
#define CL 32
#define NCH (L/CL)   // 512 chunks
#define GS 16        // chunks per group
#define NG (NCH/GS)  // 32 groups

struct Params { float M11,M12,M21,M22,s1,s2; };

__device__ inline Params get_params(const float* A_diag, const float* steps, int p){
  float A = A_diag[p]; A = A > 0.f ? A : 0.f;          // relu
  float dt = 1.f/(1.f + expf(-steps[p]));              // sigmoid
  float schur = 1.f/(1.f + dt*dt*A);
  Params q;
  q.M11 = 1.f - dt*dt*A*schur;
  q.M12 = -dt*A*schur;
  q.M21 = dt*schur;
  q.M22 = schur;
  q.s1 = q.M11*dt;   // F1 = M11*dt*Bu
  q.s2 = q.M21*dt;   // F2 = M21*dt*Bu
  return q;
}

// ---- K1: Bu = input @ Bc.T (re & im) + fused per-chunk local scan finals ----
__global__ __launch_bounds__(256) void bu_scan(const float* __restrict__ in,
                                               const float* __restrict__ B,
                                               const float* __restrict__ A_diag,
                                               const float* __restrict__ steps,
                                               float* __restrict__ BuRe,
                                               float* __restrict__ BuIm,
                                               float* __restrict__ finals){
  __shared__ float4 stile[32][32];                     // 32 l-rows x 128 h
  int c = blockIdx.x;                                  // chunk id
  int l0 = c * 32;
  const float4* gin4 = (const float4*)(in + (size_t)l0*H);
  for (int i = threadIdx.x; i < 32*32; i += 256) stile[i>>5][i&31] = gin4[i];
  __syncthreads();
  int p = threadIdx.x;
  const float4* B4 = (const float4*)(B + (size_t)p*H*2);
  float2 acc[32];
  #pragma unroll
  for (int r=0;r<32;r++) acc[r] = make_float2(0.f,0.f);
  for (int h4=0; h4<32; h4++){
    float4 b0 = B4[h4*2];
    float4 b1 = B4[h4*2+1];
    #pragma unroll
    for (int r=0;r<32;r++){
      float4 a = stile[r][h4];
      acc[r].x += a.x*b0.x + a.y*b0.z + a.z*b1.x + a.w*b1.z;
      acc[r].y += a.x*b0.y + a.y*b0.w + a.z*b1.y + a.w*b1.w;
    }
  }
  #pragma unroll
  for (int r=0;r<32;r++){
    BuRe[(size_t)(l0+r)*P + p] = acc[r].x;
    BuIm[(size_t)(l0+r)*P + p] = acc[r].y;
  }
  Params q = get_params(A_diag, steps, p);
  float r1=0.f,r2=0.f,i1=0.f,i2=0.f;
  #pragma unroll
  for (int r=0;r<32;r++){
    float ur = acc[r].x, ui = acc[r].y;
    float nr1 = q.M11*r1 + q.M12*r2 + q.s1*ur;
    float nr2 = q.M21*r1 + q.M22*r2 + q.s2*ur;
    r1=nr1; r2=nr2;
    float ni1 = q.M11*i1 + q.M12*i2 + q.s1*ui;
    float ni2 = q.M21*i1 + q.M22*i2 + q.s2*ui;
    i1=ni1; i2=ni2;
  }
  ((float2*)finals)[(size_t)(0*NCH + c)*P + p] = make_float2(r1,r2);
  ((float2*)finals)[(size_t)(1*NCH + c)*P + p] = make_float2(i1,i2);
}

// ---- K2: Ct[p][h]{re,im} = C[h][p]{re,im}  (256 KB, one-shot transpose) ----
__global__ __launch_bounds__(128) void ct_prep(const float* __restrict__ C,
                                               float* __restrict__ Ct){
  int p = blockIdx.x, h = threadIdx.x;
  float2 v = ((const float2*)C)[(size_t)h*P + p];
  ((float2*)Ct)[(size_t)p*H + h] = v;
}

// ---- K3a: per-group local scan of chunk finals (in place), group final -> gfin ----
__global__ __launch_bounds__(512) void group_scan(const float* __restrict__ A_diag,
                                                  const float* __restrict__ steps,
                                                  float* zf,
                                                  float* __restrict__ gfin){
  int tid = threadIdx.x;
  int p = tid & (P-1);
  int part = tid >> 8;
  int g = blockIdx.x;
  Params q = get_params(A_diag, steps, p);
  float a=q.M11, b=q.M12, c=q.M21, d=q.M22;
  #pragma unroll
  for (int s=0;s<5;s++){            // T = M^32
    float na=a*a+b*c, nb=a*b+b*d, nc=c*a+d*c, nd=c*b+d*d;
    a=na;b=nb;c=nc;d=nd;
  }
  float2* z2 = (float2*)zf;
  float x1=0.f, x2=0.f;
  #pragma unroll
  for (int i=0;i<GS;i++){
    size_t idx = (size_t)(part*NCH + g*GS + i)*P + p;
    float2 f = z2[idx];             // read chunk final
    z2[idx] = make_float2(x1,x2);   // overwrite with group-local carry
    float n1 = a*x1 + b*x2 + f.x;
    float n2 = c*x1 + d*x2 + f.y;
    x1=n1; x2=n2;
  }
  ((float2*)gfin)[(size_t)(part*NG + g)*P + p] = make_float2(x1,x2);
}

// ---- K3b: serial combine of 32 group finals with T_G = M^512 -> group carries ----
__global__ __launch_bounds__(512) void group_combine(const float* __restrict__ A_diag,
                                                     const float* __restrict__ steps,
                                                     const float* __restrict__ gfin,
                                                     float* __restrict__ Yarr){
  int tid = threadIdx.x;
  int p = tid & (P-1);
  int part = tid >> 8;
  Params q = get_params(A_diag, steps, p);
  float a=q.M11, b=q.M12, c=q.M21, d=q.M22;
  #pragma unroll
  for (int s=0;s<9;s++){            // T_G = M^512
    float na=a*a+b*c, nb=a*b+b*d, nc=c*a+d*c, nd=c*b+d*d;
    a=na;b=nb;c=nc;d=nd;
  }
  const float2* Z2 = (const float2*)gfin;
  float2* Y2 = (float2*)Yarr;
  float x1=0.f, x2=0.f;
  #pragma unroll
  for (int g=0; g<NG; g++){
    size_t idx = (size_t)(part*NG + g)*P + p;
    Y2[idx] = make_float2(x1,x2);
    float2 z = Z2[idx];
    float n1 = a*x1 + b*x2 + z.x;
    float n2 = c*x1 + d*x2 + z.y;
    x1=n1; x2=n2;
  }
}

// ---- K4: re-scan chunk with carry (init = T^iw * Y_g + z_c), overwrite Bu ----
__global__ __launch_bounds__(256) void scan_emit(float* __restrict__ BuRe,
                                                 float* __restrict__ BuIm,
                                                 const float* __restrict__ A_diag,
                                                 const float* __restrict__ steps,
                                                 const float* __restrict__ zloc,
                                                 const float* __restrict__ Yarr){
  int p = threadIdx.x;
  int c = blockIdx.x;
  int part = blockIdx.y;
  int g = c >> 4, iw = c & (GS-1);
  float* Bu = part ? BuIm : BuRe;
  Params q = get_params(A_diag, steps, p);
  float a=q.M11, b=q.M12, cc=q.M21, dd=q.M22;
  #pragma unroll
  for (int s=0;s<5;s++){            // T = M^32
    float na=a*a+b*cc, nb=a*b+b*dd, nc=cc*a+dd*cc, nd=cc*b+dd*dd;
    a=na;b=nb;cc=nc;dd=nd;
  }
  // S = T^iw (iw wave-uniform)
  float sa=1.f, sb=0.f, sc=0.f, sd=1.f;
  float wa=a, wb=b, wc=cc, wd=dd;
  #pragma unroll
  for (int bit=0; bit<4; bit++){
    if ((iw>>bit)&1){
      float na = wa*sa + wb*sc, nb = wa*sb + wb*sd;
      float nc = wc*sa + wd*sc, nd = wc*sb + wd*sd;
      sa=na; sb=nb; sc=nc; sd=nd;
    }
    float qa = wa*wa + wb*wc, qb = wa*wb + wb*wd;
    float qc = wc*wa + wd*wc, qd = wc*wb + wd*wd;
    wa=qa; wb=qb; wc=qc; wd=qd;
  }
  float2 Y = ((const float2*)Yarr)[(size_t)(part*NG + g)*P + p];
  float2 z = ((const float2*)zloc)[(size_t)(part*NCH + c)*P + p];
  float x1 = sa*Y.x + sb*Y.y + z.x;
  float x2 = sc*Y.x + sd*Y.y + z.y;

  float* bp = Bu + (size_t)c*CL*P + p;
  #pragma unroll 8
  for (int i=0;i<CL;i++){
    float u = bp[(size_t)i*P];
    float n1 = q.M11*x1 + q.M12*x2 + q.s1*u;
    float n2 = q.M21*x1 + q.M22*x2 + q.s2*u;
    x1 = n1; x2 = n2;
    bp[(size_t)i*P] = x2;
  }
}

// ---- K5: ys = Re(x2 @ Cc.T) + in*D -----------------------------------------
// 4 rows per wave (16 waves/CU for latency hiding). Lanes span h (2 h per lane);
// Ct loads coalesced per-lane; x2 rows read as wave-uniform float4 -> s_load_dwordx4.
__global__ __launch_bounds__(256) void out_gemm(const float* __restrict__ x2re,
                                                const float* __restrict__ x2im,
                                                const float* __restrict__ Ct,
                                                const float* __restrict__ Dv,
                                                const float* __restrict__ in,
                                                float* __restrict__ out){
  int lane = threadIdx.x & 63;
  int wu = __builtin_amdgcn_readfirstlane((int)(threadIdx.x >> 6)); // wave id, uniform
  int l0 = blockIdx.x * 16 + wu * 4;           // this wave's 4 rows
  const float* xr0 = x2re + (size_t)l0 * P;    // uniform base -> scalar loads
  const float* xi0 = x2im + (size_t)l0 * P;
  const float4* Ct4 = (const float4*)Ct;

  float acc0[4], acc1[4];
  #pragma unroll
  for (int r=0;r<4;r++){ acc0[r]=0.f; acc1[r]=0.f; }

  for (int p=0;p<P;p+=4){
    float4 cv0 = Ct4[(size_t)(p+0)*64 + lane];   // coalesced 1KB/wave each
    float4 cv1 = Ct4[(size_t)(p+1)*64 + lane];
    float4 cv2 = Ct4[(size_t)(p+2)*64 + lane];
    float4 cv3 = Ct4[(size_t)(p+3)*64 + lane];
    #pragma unroll
    for (int r=0;r<4;r++){
      float4 sr = *(const float4*)(xr0 + (size_t)r*P + p);  // uniform -> s_load_dwordx4
      float4 si = *(const float4*)(xi0 + (size_t)r*P + p);
      acc0[r] += sr.x*cv0.x - si.x*cv0.y + sr.y*cv1.x - si.y*cv1.y
               + sr.z*cv2.x - si.z*cv2.y + sr.w*cv3.x - si.w*cv3.y;
      acc1[r] += sr.x*cv0.z - si.x*cv0.w + sr.y*cv1.z - si.y*cv1.w
               + sr.z*cv2.z - si.z*cv2.w + sr.w*cv3.z - si.w*cv3.w;
    }
  }

  float2 dv = ((const float2*)Dv)[lane];
  #pragma unroll
  for (int r=0;r<4;r++){
    int l = l0 + r;
    float2 u2 = ((const float2*)(in + (size_t)l*H))[lane];
    ((float2*)(out + (size_t)l*H))[lane] =
        make_float2(acc0[r] + u2.x*dv.x, acc1[r] + u2.y*dv.y);
  }
}

extern "C" void kernel_launch(void* const* d_in, const int* in_sizes, int n_in,
                              void* d_out, int out_size, void* d_ws, size_t ws_size,
                              hipStream_t stream) {
  const float* in     = (const float*)d_in[0];   // (L,H)
  const float* A_diag = (const float*)d_in[1];   // (P,)
  const float* B      = (const float*)d_in[2];   // (P,H,2)
  const float* Cw     = (const float*)d_in[3];   // (H,P,2)
  const float* Dv     = (const float*)d_in[4];   // (H,)
  const float* steps  = (const float*)d_in[5];   // (P,)
  float* out = (float*)d_out;

  float* ws = (float*)d_ws;
  float* BuRe   = ws;                                  // L*P (16MB)
  float* BuIm   = BuRe + (size_t)L*P;                  // L*P (16MB)
  float* Ct     = BuIm + (size_t)L*P;                  // P*H*2 (256KB)
  float* finals = Ct + (size_t)P*H*2;                  // 2*NCH*P*2 (2MB) — becomes zloc in place
  float* gfin   = finals + (size_t)2*NCH*P*2;          // 2*NG*P*2 (128KB)
  float* Yarr   = gfin + (size_t)2*NG*P*2;             // 2*NG*P*2 (128KB)

  bu_scan<<<NCH, 256, 0, stream>>>(in, B, A_diag, steps, BuRe, BuIm, finals);
  ct_prep<<<P, 128, 0, stream>>>(Cw, Ct);
  group_scan<<<NG, 512, 0, stream>>>(A_diag, steps, finals, gfin);
  group_combine<<<1, 512, 0, stream>>>(A_diag, steps, gfin, Yarr);
  scan_emit<<<dim3(NCH,2), 256, 0, stream>>>(BuRe, BuIm, A_diag, steps, finals, Yarr);
  out_gemm<<<L/16, 256, 0, stream>>>(BuRe, BuIm, Ct, Dv, in, out);
}

// Round 6
// 170.026 us; speedup vs baseline: 1.1281x; 1.1281x over previous
//
#include <hip/hip_runtime.h>
#include <math.h>

#define L 16384
#define H 128
#define P 256
#define CL 32
#define NCH (L/CL)   // 512 chunks
#define GS 16        // chunks per group
#define NG (NCH/GS)  // 32 groups

struct Params { float M11,M12,M21,M22,s1,s2; };

__device__ inline Params get_params(const float* A_diag, const float* steps, int p){
  float A = A_diag[p]; A = A > 0.f ? A : 0.f;          // relu
  float dt = 1.f/(1.f + expf(-steps[p]));              // sigmoid
  float schur = 1.f/(1.f + dt*dt*A);
  Params q;
  q.M11 = 1.f - dt*dt*A*schur;
  q.M12 = -dt*A*schur;
  q.M21 = dt*schur;
  q.M22 = schur;
  q.s1 = q.M11*dt;   // F1 = M11*dt*Bu
  q.s2 = q.M21*dt;   // F2 = M21*dt*Bu
  return q;
}

// ---- K1: Bu = input @ Bc.T (re & im) + fused per-chunk local scan finals ----
__global__ __launch_bounds__(256) void bu_scan(const float* __restrict__ in,
                                               const float* __restrict__ B,
                                               const float* __restrict__ A_diag,
                                               const float* __restrict__ steps,
                                               float* __restrict__ BuRe,
                                               float* __restrict__ BuIm,
                                               float* __restrict__ finals){
  __shared__ float4 stile[32][32];                     // 32 l-rows x 128 h
  int c = blockIdx.x;                                  // chunk id
  int l0 = c * 32;
  const float4* gin4 = (const float4*)(in + (size_t)l0*H);
  for (int i = threadIdx.x; i < 32*32; i += 256) stile[i>>5][i&31] = gin4[i];
  __syncthreads();
  int p = threadIdx.x;
  const float4* B4 = (const float4*)(B + (size_t)p*H*2);
  float2 acc[32];
  #pragma unroll
  for (int r=0;r<32;r++) acc[r] = make_float2(0.f,0.f);
  for (int h4=0; h4<32; h4++){
    float4 b0 = B4[h4*2];
    float4 b1 = B4[h4*2+1];
    #pragma unroll
    for (int r=0;r<32;r++){
      float4 a = stile[r][h4];
      acc[r].x += a.x*b0.x + a.y*b0.z + a.z*b1.x + a.w*b1.z;
      acc[r].y += a.x*b0.y + a.y*b0.w + a.z*b1.y + a.w*b1.w;
    }
  }
  #pragma unroll
  for (int r=0;r<32;r++){
    BuRe[(size_t)(l0+r)*P + p] = acc[r].x;
    BuIm[(size_t)(l0+r)*P + p] = acc[r].y;
  }
  Params q = get_params(A_diag, steps, p);
  float r1=0.f,r2=0.f,i1=0.f,i2=0.f;
  #pragma unroll
  for (int r=0;r<32;r++){
    float ur = acc[r].x, ui = acc[r].y;
    float nr1 = q.M11*r1 + q.M12*r2 + q.s1*ur;
    float nr2 = q.M21*r1 + q.M22*r2 + q.s2*ur;
    r1=nr1; r2=nr2;
    float ni1 = q.M11*i1 + q.M12*i2 + q.s1*ui;
    float ni2 = q.M21*i1 + q.M22*i2 + q.s2*ui;
    i1=ni1; i2=ni2;
  }
  ((float2*)finals)[(size_t)(0*NCH + c)*P + p] = make_float2(r1,r2);
  ((float2*)finals)[(size_t)(1*NCH + c)*P + p] = make_float2(i1,i2);
}

// ---- K2: Ct[p][h]{re,im} = C[h][p]{re,im}  (256 KB, one-shot transpose) ----
__global__ __launch_bounds__(128) void ct_prep(const float* __restrict__ C,
                                               float* __restrict__ Ct){
  int p = blockIdx.x, h = threadIdx.x;
  float2 v = ((const float2*)C)[(size_t)h*P + p];
  ((float2*)Ct)[(size_t)p*H + h] = v;
}

// ---- K3a: per-group local scan of chunk finals (in place), group final -> gfin ----
__global__ __launch_bounds__(512) void group_scan(const float* __restrict__ A_diag,
                                                  const float* __restrict__ steps,
                                                  float* zf,
                                                  float* __restrict__ gfin){
  int tid = threadIdx.x;
  int p = tid & (P-1);
  int part = tid >> 8;
  int g = blockIdx.x;
  Params q = get_params(A_diag, steps, p);
  float a=q.M11, b=q.M12, c=q.M21, d=q.M22;
  #pragma unroll
  for (int s=0;s<5;s++){            // T = M^32
    float na=a*a+b*c, nb=a*b+b*d, nc=c*a+d*c, nd=c*b+d*d;
    a=na;b=nb;c=nc;d=nd;
  }
  float2* z2 = (float2*)zf;
  float x1=0.f, x2=0.f;
  #pragma unroll
  for (int i=0;i<GS;i++){
    size_t idx = (size_t)(part*NCH + g*GS + i)*P + p;
    float2 f = z2[idx];             // read chunk final
    z2[idx] = make_float2(x1,x2);   // overwrite with group-local carry
    float n1 = a*x1 + b*x2 + f.x;
    float n2 = c*x1 + d*x2 + f.y;
    x1=n1; x2=n2;
  }
  ((float2*)gfin)[(size_t)(part*NG + g)*P + p] = make_float2(x1,x2);
}

// ---- K3b: serial combine of 32 group finals with T_G = M^512 -> group carries ----
__global__ __launch_bounds__(512) void group_combine(const float* __restrict__ A_diag,
                                                     const float* __restrict__ steps,
                                                     const float* __restrict__ gfin,
                                                     float* __restrict__ Yarr){
  int tid = threadIdx.x;
  int p = tid & (P-1);
  int part = tid >> 8;
  Params q = get_params(A_diag, steps, p);
  float a=q.M11, b=q.M12, c=q.M21, d=q.M22;
  #pragma unroll
  for (int s=0;s<9;s++){            // T_G = M^512
    float na=a*a+b*c, nb=a*b+b*d, nc=c*a+d*c, nd=c*b+d*d;
    a=na;b=nb;c=nc;d=nd;
  }
  const float2* Z2 = (const float2*)gfin;
  float2* Y2 = (float2*)Yarr;
  float x1=0.f, x2=0.f;
  #pragma unroll
  for (int g=0; g<NG; g++){
    size_t idx = (size_t)(part*NG + g)*P + p;
    Y2[idx] = make_float2(x1,x2);
    float2 z = Z2[idx];
    float n1 = a*x1 + b*x2 + z.x;
    float n2 = c*x1 + d*x2 + z.y;
    x1=n1; x2=n2;
  }
}

// ---- K4: re-scan chunk with carry (init = T^iw * Y_g + z_c), overwrite Bu ----
__global__ __launch_bounds__(256) void scan_emit(float* __restrict__ BuRe,
                                                 float* __restrict__ BuIm,
                                                 const float* __restrict__ A_diag,
                                                 const float* __restrict__ steps,
                                                 const float* __restrict__ zloc,
                                                 const float* __restrict__ Yarr){
  int p = threadIdx.x;
  int c = blockIdx.x;
  int part = blockIdx.y;
  int g = c >> 4, iw = c & (GS-1);
  float* Bu = part ? BuIm : BuRe;
  Params q = get_params(A_diag, steps, p);
  float a=q.M11, b=q.M12, cc=q.M21, dd=q.M22;
  #pragma unroll
  for (int s=0;s<5;s++){            // T = M^32
    float na=a*a+b*cc, nb=a*b+b*dd, nc=cc*a+dd*cc, nd=cc*b+dd*dd;
    a=na;b=nb;cc=nc;dd=nd;
  }
  // S = T^iw (iw wave-uniform)
  float sa=1.f, sb=0.f, sc=0.f, sd=1.f;
  float wa=a, wb=b, wc=cc, wd=dd;
  #pragma unroll
  for (int bit=0; bit<4; bit++){
    if ((iw>>bit)&1){
      float na = wa*sa + wb*sc, nb = wa*sb + wb*sd;
      float nc = wc*sa + wd*sc, nd = wc*sb + wd*sd;
      sa=na; sb=nb; sc=nc; sd=nd;
    }
    float qa = wa*wa + wb*wc, qb = wa*wb + wb*wd;
    float qc = wc*wa + wd*wc, qd = wc*wb + wd*wd;
    wa=qa; wb=qb; wc=qc; wd=qd;
  }
  float2 Y = ((const float2*)Yarr)[(size_t)(part*NG + g)*P + p];
  float2 z = ((const float2*)zloc)[(size_t)(part*NCH + c)*P + p];
  float x1 = sa*Y.x + sb*Y.y + z.x;
  float x2 = sc*Y.x + sd*Y.y + z.y;

  float* bp = Bu + (size_t)c*CL*P + p;
  #pragma unroll 8
  for (int i=0;i<CL;i++){
    float u = bp[(size_t)i*P];
    float n1 = q.M11*x1 + q.M12*x2 + q.s1*u;
    float n2 = q.M21*x1 + q.M22*x2 + q.s2*u;
    x1 = n1; x2 = n2;
    bp[(size_t)i*P] = x2;
  }
}

// ---- K5: ys = Re(x2 @ Cc.T) + in*D -----------------------------------------
// x2 rows staged in LDS (32 KB/block, coalesced copy), read back as wave-uniform
// ds_read_b128 broadcasts (conflict-free). Ct via coalesced per-lane loads.
// No scalar-cache streaming. 16 rows/block, 4 rows/wave.
__global__ __launch_bounds__(256) void out_gemm(const float* __restrict__ x2re,
                                                const float* __restrict__ x2im,
                                                const float* __restrict__ Ct,
                                                const float* __restrict__ Dv,
                                                const float* __restrict__ in,
                                                float* __restrict__ out){
  __shared__ float4 sxr[16][64];               // 16 rows x 256 p
  __shared__ float4 sxi[16][64];
  int l0 = blockIdx.x * 16;
  const float4* gre = (const float4*)(x2re + (size_t)l0*P);  // 16 KB contiguous
  const float4* gim = (const float4*)(x2im + (size_t)l0*P);
  #pragma unroll
  for (int k=0;k<4;k++){
    int i = threadIdx.x + k*256;
    ((float4*)sxr)[i] = gre[i];
    ((float4*)sxi)[i] = gim[i];
  }
  __syncthreads();

  int lane = threadIdx.x & 63;
  int wu = threadIdx.x >> 6;                   // rows wu*4 .. wu*4+3
  const float4* Ct4 = (const float4*)Ct;

  float acc0[4], acc1[4];
  #pragma unroll
  for (int r=0;r<4;r++){ acc0[r]=0.f; acc1[r]=0.f; }

  for (int p4=0;p4<64;p4++){
    float4 cv0 = Ct4[(size_t)(p4*4+0)*64 + lane];  // coalesced 1KB/wave each
    float4 cv1 = Ct4[(size_t)(p4*4+1)*64 + lane];
    float4 cv2 = Ct4[(size_t)(p4*4+2)*64 + lane];
    float4 cv3 = Ct4[(size_t)(p4*4+3)*64 + lane];
    #pragma unroll
    for (int r=0;r<4;r++){
      float4 sr = sxr[wu*4+r][p4];             // uniform -> ds_read_b128 broadcast
      float4 si = sxi[wu*4+r][p4];
      acc0[r] += sr.x*cv0.x - si.x*cv0.y + sr.y*cv1.x - si.y*cv1.y
               + sr.z*cv2.x - si.z*cv2.y + sr.w*cv3.x - si.w*cv3.y;
      acc1[r] += sr.x*cv0.z - si.x*cv0.w + sr.y*cv1.z - si.y*cv1.w
               + sr.z*cv2.z - si.z*cv2.w + sr.w*cv3.z - si.w*cv3.w;
    }
  }

  float2 dv = ((const float2*)Dv)[lane];
  #pragma unroll
  for (int r=0;r<4;r++){
    int l = l0 + wu*4 + r;
    float2 u2 = ((const float2*)(in + (size_t)l*H))[lane];
    ((float2*)(out + (size_t)l*H))[lane] =
        make_float2(acc0[r] + u2.x*dv.x, acc1[r] + u2.y*dv.y);
  }
}

extern "C" void kernel_launch(void* const* d_in, const int* in_sizes, int n_in,
                              void* d_out, int out_size, void* d_ws, size_t ws_size,
                              hipStream_t stream) {
  const float* in     = (const float*)d_in[0];   // (L,H)
  const float* A_diag = (const float*)d_in[1];   // (P,)
  const float* B      = (const float*)d_in[2];   // (P,H,2)
  const float* Cw     = (const float*)d_in[3];   // (H,P,2)
  const float* Dv     = (const float*)d_in[4];   // (H,)
  const float* steps  = (const float*)d_in[5];   // (P,)
  float* out = (float*)d_out;

  float* ws = (float*)d_ws;
  float* BuRe   = ws;                                  // L*P (16MB)
  float* BuIm   = BuRe + (size_t)L*P;                  // L*P (16MB)
  float* Ct     = BuIm + (size_t)L*P;                  // P*H*2 (256KB)
  float* finals = Ct + (size_t)P*H*2;                  // 2*NCH*P*2 (2MB) — becomes zloc in place
  float* gfin   = finals + (size_t)2*NCH*P*2;          // 2*NG*P*2 (128KB)
  float* Yarr   = gfin + (size_t)2*NG*P*2;             // 2*NG*P*2 (128KB)

  bu_scan<<<NCH, 256, 0, stream>>>(in, B, A_diag, steps, BuRe, BuIm, finals);
  ct_prep<<<P, 128, 0, stream>>>(Cw, Ct);
  group_scan<<<NG, 512, 0, stream>>>(A_diag, steps, finals, gfin);
  group_combine<<<1, 512, 0, stream>>>(A_diag, steps, gfin, Yarr);
  scan_emit<<<dim3(NCH,2), 256, 0, stream>>>(BuRe, BuIm, A_diag, steps, finals, Yarr);
  out_gemm<<<L/16, 256, 0, stream>>>(BuRe, BuIm, Ct, Dv, in, out);
}

// Round 7
// 150.714 us; speedup vs baseline: 1.2727x; 1.1281x over previous
//
#include <hip/hip_runtime.h>
#include <hip/hip_bf16.h>
#include <math.h>

#define L 16384
#define H 128
#define P 256
#define CL 32
#define NCH (L/CL)   // 512 chunks
#define GS 16        // chunks per group
#define NG (NCH/GS)  // 32 groups
#define KDIM 512     // out-GEMM K = [x2re | x2im]

typedef __attribute__((ext_vector_type(8))) short short8;   // 8 bf16
typedef __attribute__((ext_vector_type(4))) float f32x4;

struct Params { float M11,M12,M21,M22,s1,s2; };

__device__ inline Params get_params(const float* A_diag, const float* steps, int p){
  float A = A_diag[p]; A = A > 0.f ? A : 0.f;          // relu
  float dt = 1.f/(1.f + expf(-steps[p]));              // sigmoid
  float schur = 1.f/(1.f + dt*dt*A);
  Params q;
  q.M11 = 1.f - dt*dt*A*schur;
  q.M12 = -dt*A*schur;
  q.M21 = dt*schur;
  q.M22 = schur;
  q.s1 = q.M11*dt;   // F1 = M11*dt*Bu
  q.s2 = q.M21*dt;   // F2 = M21*dt*Bu
  return q;
}

// ---- K1: Bu = input @ Bc.T (re & im) + fused per-chunk local scan finals ----
__global__ __launch_bounds__(256) void bu_scan(const float* __restrict__ in,
                                               const float* __restrict__ B,
                                               const float* __restrict__ A_diag,
                                               const float* __restrict__ steps,
                                               float* __restrict__ BuRe,
                                               float* __restrict__ BuIm,
                                               float* __restrict__ finals){
  __shared__ float4 stile[32][32];                     // 32 l-rows x 128 h
  int c = blockIdx.x;                                  // chunk id
  int l0 = c * 32;
  const float4* gin4 = (const float4*)(in + (size_t)l0*H);
  for (int i = threadIdx.x; i < 32*32; i += 256) stile[i>>5][i&31] = gin4[i];
  __syncthreads();
  int p = threadIdx.x;
  const float4* B4 = (const float4*)(B + (size_t)p*H*2);
  float2 acc[32];
  #pragma unroll
  for (int r=0;r<32;r++) acc[r] = make_float2(0.f,0.f);
  for (int h4=0; h4<32; h4++){
    float4 b0 = B4[h4*2];
    float4 b1 = B4[h4*2+1];
    #pragma unroll
    for (int r=0;r<32;r++){
      float4 a = stile[r][h4];
      acc[r].x += a.x*b0.x + a.y*b0.z + a.z*b1.x + a.w*b1.z;
      acc[r].y += a.x*b0.y + a.y*b0.w + a.z*b1.y + a.w*b1.w;
    }
  }
  #pragma unroll
  for (int r=0;r<32;r++){
    BuRe[(size_t)(l0+r)*P + p] = acc[r].x;
    BuIm[(size_t)(l0+r)*P + p] = acc[r].y;
  }
  Params q = get_params(A_diag, steps, p);
  float r1=0.f,r2=0.f,i1=0.f,i2=0.f;
  #pragma unroll
  for (int r=0;r<32;r++){
    float ur = acc[r].x, ui = acc[r].y;
    float nr1 = q.M11*r1 + q.M12*r2 + q.s1*ur;
    float nr2 = q.M21*r1 + q.M22*r2 + q.s2*ur;
    r1=nr1; r2=nr2;
    float ni1 = q.M11*i1 + q.M12*i2 + q.s1*ui;
    float ni2 = q.M21*i1 + q.M22*i2 + q.s2*ui;
    i1=ni1; i2=ni2;
  }
  ((float2*)finals)[(size_t)(0*NCH + c)*P + p] = make_float2(r1,r2);
  ((float2*)finals)[(size_t)(1*NCH + c)*P + p] = make_float2(i1,i2);
}

// ---- K2: build bf16 B matrix pre-swizzled to MFMA B-fragment layout ----------
// Bmat[k][n=h]: k<256 -> C[h][k].re ; k>=256 -> -C[h][k-256].im
// Bswz[((k>>3)*128 + n)*8 + (k&7)] so lane(ml,quad) reads contiguous short8.
__global__ __launch_bounds__(128) void bswz_prep(const float* __restrict__ C,
                                                 __hip_bfloat16* __restrict__ Bswz){
  int k = blockIdx.x;      // 0..511
  int n = threadIdx.x;     // 0..127
  float v = (k < P) ? C[((size_t)n*P + k)*2]
                    : -C[((size_t)n*P + (k-P))*2 + 1];
  Bswz[((size_t)(k>>3)*H + n)*8 + (k&7)] = __float2bfloat16(v);
}

// ---- K3a: per-group local scan of chunk finals (in place), group final -> gfin ----
__global__ __launch_bounds__(512) void group_scan(const float* __restrict__ A_diag,
                                                  const float* __restrict__ steps,
                                                  float* zf,
                                                  float* __restrict__ gfin){
  int tid = threadIdx.x;
  int p = tid & (P-1);
  int part = tid >> 8;
  int g = blockIdx.x;
  Params q = get_params(A_diag, steps, p);
  float a=q.M11, b=q.M12, c=q.M21, d=q.M22;
  #pragma unroll
  for (int s=0;s<5;s++){            // T = M^32
    float na=a*a+b*c, nb=a*b+b*d, nc=c*a+d*c, nd=c*b+d*d;
    a=na;b=nb;c=nc;d=nd;
  }
  float2* z2 = (float2*)zf;
  float x1=0.f, x2=0.f;
  #pragma unroll
  for (int i=0;i<GS;i++){
    size_t idx = (size_t)(part*NCH + g*GS + i)*P + p;
    float2 f = z2[idx];             // read chunk final
    z2[idx] = make_float2(x1,x2);   // overwrite with group-local carry
    float n1 = a*x1 + b*x2 + f.x;
    float n2 = c*x1 + d*x2 + f.y;
    x1=n1; x2=n2;
  }
  ((float2*)gfin)[(size_t)(part*NG + g)*P + p] = make_float2(x1,x2);
}

// ---- K3b: serial combine of 32 group finals with T_G = M^512 -> group carries ----
__global__ __launch_bounds__(512) void group_combine(const float* __restrict__ A_diag,
                                                     const float* __restrict__ steps,
                                                     const float* __restrict__ gfin,
                                                     float* __restrict__ Yarr){
  int tid = threadIdx.x;
  int p = tid & (P-1);
  int part = tid >> 8;
  Params q = get_params(A_diag, steps, p);
  float a=q.M11, b=q.M12, c=q.M21, d=q.M22;
  #pragma unroll
  for (int s=0;s<9;s++){            // T_G = M^512
    float na=a*a+b*c, nb=a*b+b*d, nc=c*a+d*c, nd=c*b+d*d;
    a=na;b=nb;c=nc;d=nd;
  }
  const float2* Z2 = (const float2*)gfin;
  float2* Y2 = (float2*)Yarr;
  float x1=0.f, x2=0.f;
  #pragma unroll
  for (int g=0; g<NG; g++){
    size_t idx = (size_t)(part*NG + g)*P + p;
    Y2[idx] = make_float2(x1,x2);
    float2 z = Z2[idx];
    float n1 = a*x1 + b*x2 + z.x;
    float n2 = c*x1 + d*x2 + z.y;
    x1=n1; x2=n2;
  }
}

// ---- K4: re-scan chunk with carry, emit x2 as bf16 A-matrix [l][k] (k=part*256+p) ----
__global__ __launch_bounds__(256) void scan_emit(const float* __restrict__ BuRe,
                                                 const float* __restrict__ BuIm,
                                                 const float* __restrict__ A_diag,
                                                 const float* __restrict__ steps,
                                                 const float* __restrict__ zloc,
                                                 const float* __restrict__ Yarr,
                                                 __hip_bfloat16* __restrict__ Abuf){
  int p = threadIdx.x;
  int c = blockIdx.x;
  int part = blockIdx.y;
  int g = c >> 4, iw = c & (GS-1);
  const float* Bu = part ? BuIm : BuRe;
  Params q = get_params(A_diag, steps, p);
  float a=q.M11, b=q.M12, cc=q.M21, dd=q.M22;
  #pragma unroll
  for (int s=0;s<5;s++){            // T = M^32
    float na=a*a+b*cc, nb=a*b+b*dd, nc=cc*a+dd*cc, nd=cc*b+dd*dd;
    a=na;b=nb;cc=nc;dd=nd;
  }
  // S = T^iw (iw wave-uniform)
  float sa=1.f, sb=0.f, sc=0.f, sd=1.f;
  float wa=a, wb=b, wc=cc, wd=dd;
  #pragma unroll
  for (int bit=0; bit<4; bit++){
    if ((iw>>bit)&1){
      float na = wa*sa + wb*sc, nb = wa*sb + wb*sd;
      float nc = wc*sa + wd*sc, nd = wc*sb + wd*sd;
      sa=na; sb=nb; sc=nc; sd=nd;
    }
    float qa = wa*wa + wb*wc, qb = wa*wb + wb*wd;
    float qc = wc*wa + wd*wc, qd = wc*wb + wd*wd;
    wa=qa; wb=qb; wc=qc; wd=qd;
  }
  float2 Y = ((const float2*)Yarr)[(size_t)(part*NG + g)*P + p];
  float2 z = ((const float2*)zloc)[(size_t)(part*NCH + c)*P + p];
  float x1 = sa*Y.x + sb*Y.y + z.x;
  float x2 = sc*Y.x + sd*Y.y + z.y;

  const float* bp = Bu + (size_t)c*CL*P + p;
  __hip_bfloat16* ap = Abuf + (size_t)c*CL*KDIM + part*P + p;
  #pragma unroll 8
  for (int i=0;i<CL;i++){
    float u = bp[(size_t)i*P];
    float n1 = q.M11*x1 + q.M12*x2 + q.s1*u;
    float n2 = q.M21*x1 + q.M22*x2 + q.s2*u;
    x1 = n1; x2 = n2;
    ap[(size_t)i*KDIM] = __float2bfloat16(x2);   // 256 consecutive shorts per row-part
  }
}

// ---- K5: out = A(bf16,16384x512) @ B(bf16,512x128) + in*D via MFMA ----------
// 1024 waves, each owns 16 rows x all 128 h (8 n-tiles). No LDS.
// A-frag: A[m=lane&15][k=quad*8+j] -> contiguous 16B/lane from row-major A.
// B-frag: from pre-swizzled Bswz (L2-resident, 128 KB).
// D-frag: col=lane&15, row=quad*4+reg.
__global__ __launch_bounds__(256) void out_mfma(const short* __restrict__ Abuf,
                                                const short* __restrict__ Bswz,
                                                const float* __restrict__ Dv,
                                                const float* __restrict__ in,
                                                float* __restrict__ out){
  int lane = threadIdx.x & 63;
  int wv = threadIdx.x >> 6;
  int m0 = (blockIdx.x * 4 + wv) * 16;
  int ml = lane & 15, quad = lane >> 4;

  const short* aptr = Abuf + (size_t)(m0 + ml)*KDIM + quad*8;
  f32x4 acc[8];
  #pragma unroll
  for (int t=0;t<8;t++) acc[t] = (f32x4){0.f,0.f,0.f,0.f};

  for (int ks=0; ks<KDIM/32; ks++){
    short8 av = *(const short8*)(aptr + ks*32);
    #pragma unroll
    for (int t=0;t<8;t++){
      short8 bv = *(const short8*)(Bswz + ((size_t)(ks*4+quad)*H + t*16 + ml)*8);
      acc[t] = __builtin_amdgcn_mfma_f32_16x16x32_bf16(av, bv, acc[t], 0, 0, 0);
    }
  }

  #pragma unroll
  for (int t=0;t<8;t++){
    int h = t*16 + ml;
    float dv = Dv[h];
    #pragma unroll
    for (int r=0;r<4;r++){
      int l = m0 + quad*4 + r;
      out[(size_t)l*H + h] = acc[t][r] + in[(size_t)l*H + h]*dv;
    }
  }
}

extern "C" void kernel_launch(void* const* d_in, const int* in_sizes, int n_in,
                              void* d_out, int out_size, void* d_ws, size_t ws_size,
                              hipStream_t stream) {
  const float* in     = (const float*)d_in[0];   // (L,H)
  const float* A_diag = (const float*)d_in[1];   // (P,)
  const float* B      = (const float*)d_in[2];   // (P,H,2)
  const float* Cw     = (const float*)d_in[3];   // (H,P,2)
  const float* Dv     = (const float*)d_in[4];   // (H,)
  const float* steps  = (const float*)d_in[5];   // (P,)
  float* out = (float*)d_out;

  float* ws = (float*)d_ws;
  float* BuRe   = ws;                                  // L*P (16MB)
  float* BuIm   = BuRe + (size_t)L*P;                  // L*P (16MB)
  __hip_bfloat16* Abuf = (__hip_bfloat16*)(BuIm + (size_t)L*P);  // L*512 bf16 (16MB)
  __hip_bfloat16* Bswz = Abuf + (size_t)L*KDIM;        // 512*128 bf16 (128KB)
  float* finals = (float*)(Bswz + (size_t)KDIM*H);     // 2*NCH*P*2 (2MB) — becomes zloc
  float* gfin   = finals + (size_t)2*NCH*P*2;          // 2*NG*P*2 (128KB)
  float* Yarr   = gfin + (size_t)2*NG*P*2;             // 2*NG*P*2 (128KB)

  bu_scan<<<NCH, 256, 0, stream>>>(in, B, A_diag, steps, BuRe, BuIm, finals);
  bswz_prep<<<KDIM, 128, 0, stream>>>(Cw, Bswz);
  group_scan<<<NG, 512, 0, stream>>>(A_diag, steps, finals, gfin);
  group_combine<<<1, 512, 0, stream>>>(A_diag, steps, gfin, Yarr);
  scan_emit<<<dim3(NCH,2), 256, 0, stream>>>(BuRe, BuIm, A_diag, steps, finals, Yarr, Abuf);
  out_mfma<<<L/64, 256, 0, stream>>>((const short*)Abuf, (const short*)Bswz, Dv, in, out);
}

// Round 8
// 136.829 us; speedup vs baseline: 1.4018x; 1.1015x over previous
//
#include <hip/hip_runtime.h>
#include <hip/hip_bf16.h>
#include <math.h>

#define L 16384
#define H 128
#define P 256
#define CL 32
#define NCH (L/CL)   // 512 chunks
#define GS 16        // chunks per group
#define NG (NCH/GS)  // 32 groups
#define KDIM 512     // out-GEMM K = [x2re | x2im]
#define NBU 512      // bu-GEMM N  = [BuRe | BuIm]

typedef __attribute__((ext_vector_type(8))) short short8;   // 8 bf16
typedef __attribute__((ext_vector_type(4))) float f32x4;

__device__ inline unsigned short f2bf(float f){          // fp32 -> bf16 RNE
  union { float f; unsigned u; } v; v.f = f;
  unsigned u = v.u;
  u += 0x7fffu + ((u >> 16) & 1u);
  return (unsigned short)(u >> 16);
}

struct Params { float M11,M12,M21,M22,s1,s2; };

__device__ inline Params get_params(const float* A_diag, const float* steps, int p){
  float A = A_diag[p]; A = A > 0.f ? A : 0.f;          // relu
  float dt = 1.f/(1.f + expf(-steps[p]));              // sigmoid
  float schur = 1.f/(1.f + dt*dt*A);
  Params q;
  q.M11 = 1.f - dt*dt*A*schur;
  q.M12 = -dt*A*schur;
  q.M21 = dt*schur;
  q.M22 = schur;
  q.s1 = q.M11*dt;   // F1 = M11*dt*Bu
  q.s2 = q.M21*dt;   // F2 = M21*dt*Bu
  return q;
}

// ---- K0: cast input to bf16 (row-major, same layout) ------------------------
__global__ __launch_bounds__(256) void cast_in(const float* __restrict__ in,
                                               unsigned short* __restrict__ inb){
  int i = blockIdx.x * 256 + threadIdx.x;      // one float4-pair (8 elems) per thread
  const float4* g = (const float4*)in;
  float4 a = g[i*2], b = g[i*2+1];
  union { short8 s; unsigned short u[8]; } o;
  o.u[0]=f2bf(a.x); o.u[1]=f2bf(a.y); o.u[2]=f2bf(a.z); o.u[3]=f2bf(a.w);
  o.u[4]=f2bf(b.x); o.u[5]=f2bf(b.y); o.u[6]=f2bf(b.z); o.u[7]=f2bf(b.w);
  ((short8*)inb)[i] = o.s;
}

// ---- K1: B weights -> bf16 MFMA-B-swizzled: BW[k=h][n] (n<256: B[p=n][h].re, else .im)
// BWswz[((k>>3)*NBU + n)*8 + (k&7)]
__global__ __launch_bounds__(512) void bwswz_prep(const float* __restrict__ B,
                                                  unsigned short* __restrict__ BWswz){
  int k = blockIdx.x;      // 0..127 (= h)
  int n = threadIdx.x;     // 0..511
  int p = n & 255, c = n >> 8;
  float v = B[((size_t)p*H + k)*2 + c];
  BWswz[((size_t)(k>>3)*NBU + n)*8 + (k&7)] = f2bf(v);
}

// ---- K2: C -> bf16 MFMA-B-swizzled for out GEMM: Bmat[k][n=h] (k<256: C.re, else -C.im)
__global__ __launch_bounds__(128) void bswz_prep(const float* __restrict__ C,
                                                 unsigned short* __restrict__ Bswz){
  int k = blockIdx.x;      // 0..511
  int n = threadIdx.x;     // 0..127
  float v = (k < P) ? C[((size_t)n*P + k)*2]
                    : -C[((size_t)n*P + (k-P))*2 + 1];
  Bswz[((size_t)(k>>3)*H + n)*8 + (k&7)] = f2bf(v);
}

// ---- K3: Bu = inb(16384x128) @ BW(128x512) via MFMA -> BuRe/BuIm fp32 -------
// 1024 blocks x 4 waves; each wave: 16 rows x 8 n-tiles (w=0: re p0-127, w=1: re
// p128-255, w=2: im p0-127, w=3: im p128-255). 16 waves/CU. No LDS.
__global__ __launch_bounds__(256) void bu_mfma(const short* __restrict__ inb,
                                               const short* __restrict__ BWswz,
                                               float* __restrict__ BuRe,
                                               float* __restrict__ BuIm){
  int lane = threadIdx.x & 63;
  int w = threadIdx.x >> 6;
  int m0 = blockIdx.x * 16;
  int ml = lane & 15, quad = lane >> 4;

  const short* aptr = inb + (size_t)(m0 + ml)*H + quad*8;
  short8 av[4];
  #pragma unroll
  for (int ks=0; ks<4; ks++) av[ks] = *(const short8*)(aptr + ks*32);

  f32x4 acc[8];
  #pragma unroll
  for (int t=0;t<8;t++) acc[t] = (f32x4){0.f,0.f,0.f,0.f};

  int nbase = w * 128;                         // this wave's n range
  #pragma unroll
  for (int ks=0; ks<4; ks++){
    #pragma unroll
    for (int t=0;t<8;t++){
      short8 bv = *(const short8*)(BWswz + ((size_t)(ks*4+quad)*NBU + nbase + t*16 + ml)*8);
      acc[t] = __builtin_amdgcn_mfma_f32_16x16x32_bf16(av[ks], bv, acc[t], 0, 0, 0);
    }
  }

  float* dst = (w >= 2) ? BuIm : BuRe;
  int pbase = (w & 1) * 128;
  #pragma unroll
  for (int t=0;t<8;t++){
    int p = pbase + t*16 + ml;
    #pragma unroll
    for (int r=0;r<4;r++){
      int l = m0 + quad*4 + r;
      dst[(size_t)l*P + p] = acc[t][r];
    }
  }
}

// ---- K4: per-chunk local scan finals (zero init) ----------------------------
__global__ __launch_bounds__(256) void scan_finals(const float* __restrict__ BuRe,
                                                   const float* __restrict__ BuIm,
                                                   const float* __restrict__ A_diag,
                                                   const float* __restrict__ steps,
                                                   float* __restrict__ finals){
  int p = threadIdx.x;
  int c = blockIdx.x;
  int part = blockIdx.y;
  const float* Bu = part ? BuIm : BuRe;
  Params q = get_params(A_diag, steps, p);
  float x1 = 0.f, x2 = 0.f;
  const float* bp = Bu + (size_t)c*CL*P + p;
  #pragma unroll 8
  for (int i=0;i<CL;i++){
    float u = bp[(size_t)i*P];
    float n1 = q.M11*x1 + q.M12*x2 + q.s1*u;
    float n2 = q.M21*x1 + q.M22*x2 + q.s2*u;
    x1 = n1; x2 = n2;
  }
  ((float2*)finals)[(size_t)(part*NCH + c)*P + p] = make_float2(x1,x2);
}

// ---- K5a: per-group local scan of chunk finals (in place), group final -> gfin ----
__global__ __launch_bounds__(512) void group_scan(const float* __restrict__ A_diag,
                                                  const float* __restrict__ steps,
                                                  float* zf,
                                                  float* __restrict__ gfin){
  int tid = threadIdx.x;
  int p = tid & (P-1);
  int part = tid >> 8;
  int g = blockIdx.x;
  Params q = get_params(A_diag, steps, p);
  float a=q.M11, b=q.M12, c=q.M21, d=q.M22;
  #pragma unroll
  for (int s=0;s<5;s++){            // T = M^32
    float na=a*a+b*c, nb=a*b+b*d, nc=c*a+d*c, nd=c*b+d*d;
    a=na;b=nb;c=nc;d=nd;
  }
  float2* z2 = (float2*)zf;
  float x1=0.f, x2=0.f;
  #pragma unroll
  for (int i=0;i<GS;i++){
    size_t idx = (size_t)(part*NCH + g*GS + i)*P + p;
    float2 f = z2[idx];             // read chunk final
    z2[idx] = make_float2(x1,x2);   // overwrite with group-local carry
    float n1 = a*x1 + b*x2 + f.x;
    float n2 = c*x1 + d*x2 + f.y;
    x1=n1; x2=n2;
  }
  ((float2*)gfin)[(size_t)(part*NG + g)*P + p] = make_float2(x1,x2);
}

// ---- K5b: serial combine of 32 group finals with T_G = M^512 -> group carries ----
__global__ __launch_bounds__(512) void group_combine(const float* __restrict__ A_diag,
                                                     const float* __restrict__ steps,
                                                     const float* __restrict__ gfin,
                                                     float* __restrict__ Yarr){
  int tid = threadIdx.x;
  int p = tid & (P-1);
  int part = tid >> 8;
  Params q = get_params(A_diag, steps, p);
  float a=q.M11, b=q.M12, c=q.M21, d=q.M22;
  #pragma unroll
  for (int s=0;s<9;s++){            // T_G = M^512
    float na=a*a+b*c, nb=a*b+b*d, nc=c*a+d*c, nd=c*b+d*d;
    a=na;b=nb;c=nc;d=nd;
  }
  const float2* Z2 = (const float2*)gfin;
  float2* Y2 = (float2*)Yarr;
  float x1=0.f, x2=0.f;
  #pragma unroll
  for (int g=0; g<NG; g++){
    size_t idx = (size_t)(part*NG + g)*P + p;
    Y2[idx] = make_float2(x1,x2);
    float2 z = Z2[idx];
    float n1 = a*x1 + b*x2 + z.x;
    float n2 = c*x1 + d*x2 + z.y;
    x1=n1; x2=n2;
  }
}

// ---- K6: re-scan chunk with carry, emit x2 as bf16 A-matrix [l][k] (k=part*256+p) ----
__global__ __launch_bounds__(256) void scan_emit(const float* __restrict__ BuRe,
                                                 const float* __restrict__ BuIm,
                                                 const float* __restrict__ A_diag,
                                                 const float* __restrict__ steps,
                                                 const float* __restrict__ zloc,
                                                 const float* __restrict__ Yarr,
                                                 unsigned short* __restrict__ Abuf){
  int p = threadIdx.x;
  int c = blockIdx.x;
  int part = blockIdx.y;
  int g = c >> 4, iw = c & (GS-1);
  const float* Bu = part ? BuIm : BuRe;
  Params q = get_params(A_diag, steps, p);
  float a=q.M11, b=q.M12, cc=q.M21, dd=q.M22;
  #pragma unroll
  for (int s=0;s<5;s++){            // T = M^32
    float na=a*a+b*cc, nb=a*b+b*dd, nc=cc*a+dd*cc, nd=cc*b+dd*dd;
    a=na;b=nb;cc=nc;dd=nd;
  }
  // S = T^iw (iw wave-uniform)
  float sa=1.f, sb=0.f, sc=0.f, sd=1.f;
  float wa=a, wb=b, wc=cc, wd=dd;
  #pragma unroll
  for (int bit=0; bit<4; bit++){
    if ((iw>>bit)&1){
      float na = wa*sa + wb*sc, nb = wa*sb + wb*sd;
      float nc = wc*sa + wd*sc, nd = wc*sb + wd*sd;
      sa=na; sb=nb; sc=nc; sd=nd;
    }
    float qa = wa*wa + wb*wc, qb = wa*wb + wb*wd;
    float qc = wc*wa + wd*wc, qd = wc*wb + wd*wd;
    wa=qa; wb=qb; wc=qc; wd=qd;
  }
  float2 Y = ((const float2*)Yarr)[(size_t)(part*NG + g)*P + p];
  float2 z = ((const float2*)zloc)[(size_t)(part*NCH + c)*P + p];
  float x1 = sa*Y.x + sb*Y.y + z.x;
  float x2 = sc*Y.x + sd*Y.y + z.y;

  const float* bp = Bu + (size_t)c*CL*P + p;
  unsigned short* ap = Abuf + (size_t)c*CL*KDIM + part*P + p;
  #pragma unroll 8
  for (int i=0;i<CL;i++){
    float u = bp[(size_t)i*P];
    float n1 = q.M11*x1 + q.M12*x2 + q.s1*u;
    float n2 = q.M21*x1 + q.M22*x2 + q.s2*u;
    x1 = n1; x2 = n2;
    ap[(size_t)i*KDIM] = f2bf(x2);
  }
}

// ---- K7: out = A(bf16,16384x512) @ B(bf16,512x128) + in*D via MFMA ----------
__global__ __launch_bounds__(256) void out_mfma(const short* __restrict__ Abuf,
                                                const short* __restrict__ Bswz,
                                                const float* __restrict__ Dv,
                                                const float* __restrict__ in,
                                                float* __restrict__ out){
  int lane = threadIdx.x & 63;
  int wv = threadIdx.x >> 6;
  int m0 = (blockIdx.x * 4 + wv) * 16;
  int ml = lane & 15, quad = lane >> 4;

  const short* aptr = Abuf + (size_t)(m0 + ml)*KDIM + quad*8;
  f32x4 acc[8];
  #pragma unroll
  for (int t=0;t<8;t++) acc[t] = (f32x4){0.f,0.f,0.f,0.f};

  for (int ks=0; ks<KDIM/32; ks++){
    short8 av = *(const short8*)(aptr + ks*32);
    #pragma unroll
    for (int t=0;t<8;t++){
      short8 bv = *(const short8*)(Bswz + ((size_t)(ks*4+quad)*H + t*16 + ml)*8);
      acc[t] = __builtin_amdgcn_mfma_f32_16x16x32_bf16(av, bv, acc[t], 0, 0, 0);
    }
  }

  #pragma unroll
  for (int t=0;t<8;t++){
    int h = t*16 + ml;
    float dv = Dv[h];
    #pragma unroll
    for (int r=0;r<4;r++){
      int l = m0 + quad*4 + r;
      out[(size_t)l*H + h] = acc[t][r] + in[(size_t)l*H + h]*dv;
    }
  }
}

extern "C" void kernel_launch(void* const* d_in, const int* in_sizes, int n_in,
                              void* d_out, int out_size, void* d_ws, size_t ws_size,
                              hipStream_t stream) {
  const float* in     = (const float*)d_in[0];   // (L,H)
  const float* A_diag = (const float*)d_in[1];   // (P,)
  const float* B      = (const float*)d_in[2];   // (P,H,2)
  const float* Cw     = (const float*)d_in[3];   // (H,P,2)
  const float* Dv     = (const float*)d_in[4];   // (H,)
  const float* steps  = (const float*)d_in[5];   // (P,)
  float* out = (float*)d_out;

  float* ws = (float*)d_ws;
  float* BuRe   = ws;                                        // L*P fp32 (16MB)
  float* BuIm   = BuRe + (size_t)L*P;                        // L*P fp32 (16MB)
  unsigned short* Abuf = (unsigned short*)(BuIm + (size_t)L*P); // L*512 bf16 (16MB)
  unsigned short* inb  = Abuf + (size_t)L*KDIM;              // L*H bf16 (4MB)
  unsigned short* BWswz= inb + (size_t)L*H;                  // 128*512 bf16 (128KB)
  unsigned short* Bswz = BWswz + (size_t)H*NBU;              // 512*128 bf16 (128KB)
  float* finals = (float*)(Bswz + (size_t)KDIM*H);           // 2*NCH*P*2 (2MB) — becomes zloc
  float* gfin   = finals + (size_t)2*NCH*P*2;                // 2*NG*P*2 (128KB)
  float* Yarr   = gfin + (size_t)2*NG*P*2;                   // 2*NG*P*2 (128KB)

  cast_in<<<(L*H)/(8*256), 256, 0, stream>>>(in, inb);
  bwswz_prep<<<H, 512, 0, stream>>>(B, BWswz);
  bswz_prep<<<KDIM, 128, 0, stream>>>(Cw, Bswz);
  bu_mfma<<<L/16, 256, 0, stream>>>((const short*)inb, (const short*)BWswz, BuRe, BuIm);
  scan_finals<<<dim3(NCH,2), 256, 0, stream>>>(BuRe, BuIm, A_diag, steps, finals);
  group_scan<<<NG, 512, 0, stream>>>(A_diag, steps, finals, gfin);
  group_combine<<<1, 512, 0, stream>>>(A_diag, steps, gfin, Yarr);
  scan_emit<<<dim3(NCH,2), 256, 0, stream>>>(BuRe, BuIm, A_diag, steps, finals, Yarr, Abuf);
  out_mfma<<<L/64, 256, 0, stream>>>((const short*)Abuf, (const short*)Bswz, Dv, in, out);
}

// Round 9
// 109.160 us; speedup vs baseline: 1.7571x; 1.2535x over previous
//
#include <hip/hip_runtime.h>
#include <hip/hip_bf16.h>
#include <math.h>

#define L 16384
#define H 128
#define P 256
#define CL 32
#define NCH (L/CL)   // 512 chunks
#define GS 16        // chunks per group
#define NG (NCH/GS)  // 32 groups
#define KDIM 512     // out-GEMM K = [x2re | x2im]
#define NBU 512      // bu-GEMM N  = [BuRe | BuIm]

typedef __attribute__((ext_vector_type(8))) short short8;   // 8 bf16
typedef __attribute__((ext_vector_type(4))) float f32x4;

__device__ inline unsigned short f2bf(float f){          // fp32 -> bf16 RNE
  union { float f; unsigned u; } v; v.f = f;
  unsigned u = v.u;
  u += 0x7fffu + ((u >> 16) & 1u);
  return (unsigned short)(u >> 16);
}
__device__ inline float bf2f(unsigned short s){
  union { unsigned u; float f; } v; v.u = ((unsigned)s) << 16;
  return v.f;
}

struct Params { float M11,M12,M21,M22,s1,s2; };

__device__ inline Params get_params(const float* A_diag, const float* steps, int p){
  float A = A_diag[p]; A = A > 0.f ? A : 0.f;          // relu
  float dt = 1.f/(1.f + expf(-steps[p]));              // sigmoid
  float schur = 1.f/(1.f + dt*dt*A);
  Params q;
  q.M11 = 1.f - dt*dt*A*schur;
  q.M12 = -dt*A*schur;
  q.M21 = dt*schur;
  q.M22 = schur;
  q.s1 = q.M11*dt;   // F1 = M11*dt*Bu
  q.s2 = q.M21*dt;   // F2 = M21*dt*Bu
  return q;
}

// ---- K0: cast input to bf16 (row-major, same layout) ------------------------
__global__ __launch_bounds__(256) void cast_in(const float* __restrict__ in,
                                               unsigned short* __restrict__ inb){
  int i = blockIdx.x * 256 + threadIdx.x;      // 8 elems per thread
  const float4* g = (const float4*)in;
  float4 a = g[i*2], b = g[i*2+1];
  union { short8 s; unsigned short u[8]; } o;
  o.u[0]=f2bf(a.x); o.u[1]=f2bf(a.y); o.u[2]=f2bf(a.z); o.u[3]=f2bf(a.w);
  o.u[4]=f2bf(b.x); o.u[5]=f2bf(b.y); o.u[6]=f2bf(b.z); o.u[7]=f2bf(b.w);
  ((short8*)inb)[i] = o.s;
}

// ---- K1: B weights -> bf16 MFMA-B-swizzled: BW[k=h][n] (n<256: B[p=n][h].re, else .im)
__global__ __launch_bounds__(512) void bwswz_prep(const float* __restrict__ B,
                                                  unsigned short* __restrict__ BWswz){
  int k = blockIdx.x;      // 0..127 (= h)
  int n = threadIdx.x;     // 0..511
  int p = n & 255, c = n >> 8;
  float v = B[((size_t)p*H + k)*2 + c];
  BWswz[((size_t)(k>>3)*NBU + n)*8 + (k&7)] = f2bf(v);
}

// ---- K2: C -> bf16 MFMA-B-swizzled for out GEMM: Bmat[k][n=h] (k<256: C.re, else -C.im)
__global__ __launch_bounds__(128) void bswz_prep(const float* __restrict__ C,
                                                 unsigned short* __restrict__ Bswz){
  int k = blockIdx.x;      // 0..511
  int n = threadIdx.x;     // 0..127
  float v = (k < P) ? C[((size_t)n*P + k)*2]
                    : -C[((size_t)n*P + (k-P))*2 + 1];
  Bswz[((size_t)(k>>3)*H + n)*8 + (k&7)] = f2bf(v);
}

// ---- shared device helper: MFMA one chunk of Bu into LDS (bf16) -------------
// block = 512 threads, chunk c: Bu[32 rows][512 n] -> sBu (row stride NBU+8).
__device__ inline void chunk_bu_to_lds(int c, const short* __restrict__ inb,
                                       const short* __restrict__ BWswz,
                                       unsigned short (*sBu)[NBU+8]){
  int tid = threadIdx.x;
  int lane = tid & 63, w = tid >> 6;           // 8 waves
  int ml = lane & 15, quad = lane >> 4;
  int mt = w & 1, ng = w >> 1;                 // m-tile, n-tile group (8 tiles)
  int lm0 = mt*16;
  const short* aptr = inb + (size_t)(c*CL + lm0 + ml)*H + quad*8;
  short8 av[4];
  #pragma unroll
  for (int ks=0; ks<4; ks++) av[ks] = *(const short8*)(aptr + ks*32);
  f32x4 acc[8];
  #pragma unroll
  for (int t=0;t<8;t++) acc[t] = (f32x4){0.f,0.f,0.f,0.f};
  #pragma unroll
  for (int ks=0; ks<4; ks++){
    #pragma unroll
    for (int t=0;t<8;t++){
      int n0 = (ng*8 + t)*16;
      short8 bv = *(const short8*)(BWswz + ((size_t)(ks*4+quad)*NBU + n0 + ml)*8);
      acc[t] = __builtin_amdgcn_mfma_f32_16x16x32_bf16(av[ks], bv, acc[t], 0, 0, 0);
    }
  }
  #pragma unroll
  for (int t=0;t<8;t++){
    int n = (ng*8+t)*16 + ml;
    #pragma unroll
    for (int r=0;r<4;r++)
      sBu[lm0 + quad*4 + r][n] = f2bf(acc[t][r]);
  }
}

// ---- K3: phase 1 — per-chunk MFMA Bu -> LDS -> local scan -> chunk finals ----
__global__ __launch_bounds__(512) void bu_finals(const short* __restrict__ inb,
                                                 const short* __restrict__ BWswz,
                                                 const float* __restrict__ A_diag,
                                                 const float* __restrict__ steps,
                                                 float* __restrict__ finals){
  __shared__ unsigned short sBu[CL][NBU+8];    // 33.3 KB
  int c = blockIdx.x;
  chunk_bu_to_lds(c, inb, BWswz, sBu);
  __syncthreads();
  int tid = threadIdx.x;
  int p = tid & 255, part = tid >> 8;
  Params q = get_params(A_diag, steps, p);
  float x1=0.f, x2=0.f;
  #pragma unroll
  for (int i=0;i<CL;i++){
    float u = bf2f(sBu[i][part*256 + p]);
    float n1 = q.M11*x1 + q.M12*x2 + q.s1*u;
    float n2 = q.M21*x1 + q.M22*x2 + q.s2*u;
    x1 = n1; x2 = n2;
  }
  ((float2*)finals)[(size_t)(part*NCH + c)*P + p] = make_float2(x1,x2);
}

// ---- K4a: per-group local scan of chunk finals (in place), group final -> gfin ----
__global__ __launch_bounds__(512) void group_scan(const float* __restrict__ A_diag,
                                                  const float* __restrict__ steps,
                                                  float* zf,
                                                  float* __restrict__ gfin){
  int tid = threadIdx.x;
  int p = tid & (P-1);
  int part = tid >> 8;
  int g = blockIdx.x;
  Params q = get_params(A_diag, steps, p);
  float a=q.M11, b=q.M12, c=q.M21, d=q.M22;
  #pragma unroll
  for (int s=0;s<5;s++){            // T = M^32
    float na=a*a+b*c, nb=a*b+b*d, nc=c*a+d*c, nd=c*b+d*d;
    a=na;b=nb;c=nc;d=nd;
  }
  float2* z2 = (float2*)zf;
  float x1=0.f, x2=0.f;
  #pragma unroll
  for (int i=0;i<GS;i++){
    size_t idx = (size_t)(part*NCH + g*GS + i)*P + p;
    float2 f = z2[idx];             // read chunk final
    z2[idx] = make_float2(x1,x2);   // overwrite with group-local carry
    float n1 = a*x1 + b*x2 + f.x;
    float n2 = c*x1 + d*x2 + f.y;
    x1=n1; x2=n2;
  }
  ((float2*)gfin)[(size_t)(part*NG + g)*P + p] = make_float2(x1,x2);
}

// ---- K4b: serial combine of 32 group finals with T_G = M^512 -> group carries ----
__global__ __launch_bounds__(512) void group_combine(const float* __restrict__ A_diag,
                                                     const float* __restrict__ steps,
                                                     const float* __restrict__ gfin,
                                                     float* __restrict__ Yarr){
  int tid = threadIdx.x;
  int p = tid & (P-1);
  int part = tid >> 8;
  Params q = get_params(A_diag, steps, p);
  float a=q.M11, b=q.M12, c=q.M21, d=q.M22;
  #pragma unroll
  for (int s=0;s<9;s++){            // T_G = M^512
    float na=a*a+b*c, nb=a*b+b*d, nc=c*a+d*c, nd=c*b+d*d;
    a=na;b=nb;c=nc;d=nd;
  }
  const float2* Z2 = (const float2*)gfin;
  float2* Y2 = (float2*)Yarr;
  float x1=0.f, x2=0.f;
  #pragma unroll
  for (int g=0; g<NG; g++){
    size_t idx = (size_t)(part*NG + g)*P + p;
    Y2[idx] = make_float2(x1,x2);
    float2 z = Z2[idx];
    float n1 = a*x1 + b*x2 + z.x;
    float n2 = c*x1 + d*x2 + z.y;
    x1=n1; x2=n2;
  }
}

// ---- K5: phase 3 fused — MFMA Bu -> LDS -> scan w/ carry (in-place x2, A-layout)
//          -> out = x2 @ Bswz + in*D via MFMA ---------------------------------
__global__ __launch_bounds__(512) void fused_out(const short* __restrict__ inb,
                                                 const short* __restrict__ BWswz,
                                                 const short* __restrict__ Bswz,
                                                 const float* __restrict__ A_diag,
                                                 const float* __restrict__ steps,
                                                 const float* __restrict__ zloc,
                                                 const float* __restrict__ Yarr,
                                                 const float* __restrict__ Dv,
                                                 const float* __restrict__ in,
                                                 float* __restrict__ out){
  __shared__ unsigned short sX[CL][KDIM+8];    // Bu, overwritten in place by x2
  int c = blockIdx.x;
  chunk_bu_to_lds(c, inb, BWswz, sX);
  __syncthreads();

  // --- scan with carry; x2 overwrites Bu slot (same thread, same addr) ---
  int tid = threadIdx.x;
  {
    int p = tid & 255, part = tid >> 8;
    int g = c >> 4, iw = c & (GS-1);
    Params q = get_params(A_diag, steps, p);
    float a=q.M11, b=q.M12, cc=q.M21, dd=q.M22;
    #pragma unroll
    for (int s=0;s<5;s++){          // T = M^32
      float na=a*a+b*cc, nb=a*b+b*dd, nc=cc*a+dd*cc, nd=cc*b+dd*dd;
      a=na;b=nb;cc=nc;dd=nd;
    }
    float sa=1.f, sb=0.f, sc=0.f, sd=1.f;     // S = T^iw (iw wave-uniform)
    float wa=a, wb=b, wc=cc, wd=dd;
    #pragma unroll
    for (int bit=0; bit<4; bit++){
      if ((iw>>bit)&1){
        float na = wa*sa + wb*sc, nb = wa*sb + wb*sd;
        float nc = wc*sa + wd*sc, nd = wc*sb + wd*sd;
        sa=na; sb=nb; sc=nc; sd=nd;
      }
      float qa = wa*wa + wb*wc, qb = wa*wb + wb*wd;
      float qc = wc*wa + wd*wc, qd = wc*wb + wd*wd;
      wa=qa; wb=qb; wc=qc; wd=qd;
    }
    float2 Y = ((const float2*)Yarr)[(size_t)(part*NG + g)*P + p];
    float2 z = ((const float2*)zloc)[(size_t)(part*NCH + c)*P + p];
    float x1 = sa*Y.x + sb*Y.y + z.x;
    float x2 = sc*Y.x + sd*Y.y + z.y;
    #pragma unroll
    for (int i=0;i<CL;i++){
      float u = bf2f(sX[i][part*256 + p]);
      float n1 = q.M11*x1 + q.M12*x2 + q.s1*u;
      float n2 = q.M21*x1 + q.M22*x2 + q.s2*u;
      x1 = n1; x2 = n2;
      sX[i][part*256 + p] = f2bf(x2);
    }
  }
  __syncthreads();

  // --- out GEMM: 32 rows x 128 h, A from LDS, 2 n-tiles per wave ---
  int lane = tid & 63, w = tid >> 6;
  int ml = lane & 15, quad = lane >> 4;
  int mt = w & 1;                               // rows mt*16..
  int ntb = (w >> 1) * 2;                       // n-tiles ntb, ntb+1
  f32x4 acc[2];
  acc[0] = (f32x4){0.f,0.f,0.f,0.f};
  acc[1] = (f32x4){0.f,0.f,0.f,0.f};
  for (int ks=0; ks<KDIM/32; ks++){
    short8 av = *(const short8*)&sX[mt*16 + ml][ks*32 + quad*8];
    #pragma unroll
    for (int j=0;j<2;j++){
      short8 bv = *(const short8*)(Bswz + ((size_t)(ks*4+quad)*H + (ntb+j)*16 + ml)*8);
      acc[j] = __builtin_amdgcn_mfma_f32_16x16x32_bf16(av, bv, acc[j], 0, 0, 0);
    }
  }
  #pragma unroll
  for (int j=0;j<2;j++){
    int h = (ntb+j)*16 + ml;
    float dv = Dv[h];
    #pragma unroll
    for (int r=0;r<4;r++){
      int l = c*CL + mt*16 + quad*4 + r;
      out[(size_t)l*H + h] = acc[j][r] + in[(size_t)l*H + h]*dv;
    }
  }
}

extern "C" void kernel_launch(void* const* d_in, const int* in_sizes, int n_in,
                              void* d_out, int out_size, void* d_ws, size_t ws_size,
                              hipStream_t stream) {
  const float* in     = (const float*)d_in[0];   // (L,H)
  const float* A_diag = (const float*)d_in[1];   // (P,)
  const float* B      = (const float*)d_in[2];   // (P,H,2)
  const float* Cw     = (const float*)d_in[3];   // (H,P,2)
  const float* Dv     = (const float*)d_in[4];   // (H,)
  const float* steps  = (const float*)d_in[5];   // (P,)
  float* out = (float*)d_out;

  unsigned short* inb  = (unsigned short*)d_ws;              // L*H bf16 (4MB)
  unsigned short* BWswz= inb + (size_t)L*H;                  // 128*512 bf16 (128KB)
  unsigned short* Bswz = BWswz + (size_t)H*NBU;              // 512*128 bf16 (128KB)
  float* finals = (float*)(Bswz + (size_t)KDIM*H);           // 2*NCH*P*2 (2MB) — becomes zloc
  float* gfin   = finals + (size_t)2*NCH*P*2;                // 2*NG*P*2 (128KB)
  float* Yarr   = gfin + (size_t)2*NG*P*2;                   // 2*NG*P*2 (128KB)

  cast_in<<<(L*H)/(8*256), 256, 0, stream>>>(in, inb);
  bwswz_prep<<<H, 512, 0, stream>>>(B, BWswz);
  bswz_prep<<<KDIM, 128, 0, stream>>>(Cw, Bswz);
  bu_finals<<<NCH, 512, 0, stream>>>((const short*)inb, (const short*)BWswz,
                                     A_diag, steps, finals);
  group_scan<<<NG, 512, 0, stream>>>(A_diag, steps, finals, gfin);
  group_combine<<<1, 512, 0, stream>>>(A_diag, steps, gfin, Yarr);
  fused_out<<<NCH, 512, 0, stream>>>((const short*)inb, (const short*)BWswz,
                                     (const short*)Bswz, A_diag, steps,
                                     finals, Yarr, Dv, in, out);
}